// Round 19
// baseline (187.187 us; speedup 1.0000x reference)
//
#include <hip/hip_runtime.h>
#include <hip/hip_bf16.h>

// GaussianMMD: out = mean(Kxx)+mean(Kyy)-2*mean(Kxy), K=exp(-||a-b||^2/2048)
// R19 = R18 (int8 MFMA BK=128B, exact int32 Gram, 4-phase 1-barrier/phase,
// grid-2048, bh-hoist) with p1's barrier ALSO removed (read-free phase) ->
// 3 barriers/K-tile. Publication chain unchanged (each vmcnt still followed
// by a barrier before dependent reads); WAR separation >=3 barriers.

#define N_ROWS 8192
#define DIM 1024
#define TWO_N 16384
#define BT 256
#define BKB 128                      // K-tile in BYTES (i8 elems)
#define NT2 64
#define NBLK2 (NT2 * (NT2 + 1) / 2) // 2080
#define GRID2 2048
#define NKT (DIM / BKB)             // 8
#define QSCL (127.0f / 6.0f)
#define S2 ((6.0f / 127.0f) * (6.0f / 127.0f))
#define KFAC (-S2 / 2048.0f)

typedef int i32x4 __attribute__((ext_vector_type(4)));

typedef __attribute__((address_space(3))) unsigned int lds_u32_t;
typedef const __attribute__((address_space(1))) unsigned int glb_u32_t;

__device__ __forceinline__ void gload16(const void* g, void* l) {
    __builtin_amdgcn_global_load_lds((glb_u32_t*)g, (lds_u32_t*)l, 16, 0, 0);
}

#define SBAR() do { __builtin_amdgcn_sched_barrier(0); \
                    __builtin_amdgcn_s_barrier();      \
                    __builtin_amdgcn_sched_barrier(0); } while (0)
#define VMCNT(n) asm volatile("s_waitcnt vmcnt(" #n ")" ::: "memory")

// ---- convert fp32 -> int8 (fixed scale), norms in exact int32 ----
__global__ __launch_bounds__(256) void mmd_convert_i8(const float* __restrict__ x,
                                                      const float* __restrict__ y,
                                                      int* __restrict__ zq,
                                                      int* __restrict__ zn) {
    int row = blockIdx.x * 4 + (threadIdx.x >> 6);
    int lane = threadIdx.x & 63;
    const float* p = (row < N_ROWS) ? (x + (size_t)row * DIM)
                                    : (y + (size_t)(row - N_ROWS) * DIM);
    int* q = zq + (size_t)row * (DIM / 4);
    int s = 0;
#pragma unroll
    for (int c = 0; c < 4; ++c) {
        int widx = lane + c * 64;
        float4 v = *(const float4*)(p + widx * 4);
        int q0 = (int)rintf(fminf(fmaxf(v.x * QSCL, -127.0f), 127.0f));
        int q1 = (int)rintf(fminf(fmaxf(v.y * QSCL, -127.0f), 127.0f));
        int q2 = (int)rintf(fminf(fmaxf(v.z * QSCL, -127.0f), 127.0f));
        int q3 = (int)rintf(fminf(fmaxf(v.w * QSCL, -127.0f), 127.0f));
        s += q0 * q0 + q1 * q1 + q2 * q2 + q3 * q3;
        q[widx] = (q0 & 0xff) | ((q1 & 0xff) << 8) | ((q2 & 0xff) << 16) | ((q3 & 0xff) << 24);
    }
#pragma unroll
    for (int o = 32; o > 0; o >>= 1) s += __shfl_down(s, o);
    if (lane == 0) zn[row] = s;
}

// ---- main: 256x256 tile, 8 waves, 3 barriers/K-tile, BK=128 i8 ----
__global__ __launch_bounds__(512, 2) void mmd_main_i8(const char* __restrict__ zq,
                                                      const int* __restrict__ zn,
                                                      double* __restrict__ partials) {
    __shared__ __align__(16) char lsA[2][BT * BKB];  // 64 KiB
    __shared__ __align__(16) char lsB[2][BT * BKB];  // 64 KiB
    __shared__ double red[8];

    const int tid = threadIdx.x;
    const int bid0 = blockIdx.x;

    const int l = tid & 63;
    const int wid = tid >> 6;
    const int wr = wid >> 2;  // 0..1
    const int wc = wid & 3;   // 0..3
    const int fr = l & 15;
    const int fg = l >> 4;    // 16B-chunk within 64-K half

    // staging: thread t -> LDS row=t>>3 (0..63), slot=t&7; global chunk = slot^(row&7)
    const int srow = tid >> 3;
    const int cswz = ((tid & 7) ^ ((tid >> 3) & 7)) * 16;
    char* lA = &lsA[0][0];
    char* lB = &lsB[0][0];
    const int t16 = tid * 16;

#define STG_A(buf, half, kt) do {                                             \
        const char* g_ = pA + (size_t)((half) * 128) * DIM + (kt) * BKB;      \
        gload16(g_,            lA + (buf) * 32768 + (half) * 16384 + t16);        \
        gload16(g_ + 64 * DIM, lA + (buf) * 32768 + (half) * 16384 + 8192 + t16); \
    } while (0)
#define STG_B(buf, half, kt) do {                                             \
        const char* g_ = pB + (size_t)((half) * 128) * DIM + (kt) * BKB;      \
        gload16(g_,            lB + (buf) * 32768 + (half) * 16384 + t16);        \
        gload16(g_ + 64 * DIM, lB + (buf) * 32768 + (half) * 16384 + 8192 + t16); \
    } while (0)
// frag reads: row r, K-half s, chunk fg -> phys slot (s*4+fg)^(r&7); r&7 == fr&7
#define DS_A(buf, m, s) (*(const i32x4*)(lA + (buf) * 32768 + \
        (wr * 128 + (m) * 16 + fr) * BKB + ((((s) * 4 + fg) ^ (fr & 7)) << 4)))
#define DS_B(buf, n, s) (*(const i32x4*)(lB + (buf) * 32768 + \
        (wc * 64 + (n) * 16 + fr) * BKB + ((((s) * 4 + fg) ^ (fr & 7)) << 4)))

    const int npairs = (bid0 < NBLK2 - GRID2) ? 2 : 1;  // blocks 0..31 do 2 pairs

#pragma unroll 1
    for (int pp = 0; pp < npairs; ++pp) {
        const int pid = pp ? (GRID2 + bid0) : bid0;
        const int bid = (pid & 7) * (NBLK2 / 8) + (pid >> 3);  // XCD swizzle

        int tj = (int)((sqrtf(8.0f * (float)bid + 1.0f) - 1.0f) * 0.5f);
        while ((tj + 1) * (tj + 2) / 2 <= bid) ++tj;
        while (tj * (tj + 1) / 2 > bid) --tj;
        const int ti = bid - tj * (tj + 1) / 2;

        const int rA = ti * BT, rB = tj * BT;
        const float w = ((ti < 32) == (tj < 32)) ? 1.0f : -1.0f;
        const float factor = (ti == tj) ? w : 2.0f * w;

        const char* pA = zq + (size_t)(rA + srow) * DIM + cswz;
        const char* pB = zq + (size_t)(rB + srow) * DIM + cswz;

        i32x4 acc[8][4];
#pragma unroll
        for (int m = 0; m < 8; ++m)
#pragma unroll
            for (int n = 0; n < 4; ++n) acc[m][n] = (i32x4){0, 0, 0, 0};

        // prologue: full tile 0 + A0 of tile 1 (10 loads); retire tile 0
        STG_A(0, 0, 0);
        STG_B(0, 0, 0);
        STG_B(0, 1, 0);
        STG_A(0, 1, 0);
        STG_A(1, 0, 1);
        VMCNT(2);
        SBAR();

        i32x4 a[4][2], b_cur[2][2], b_hi[2][2], b_nxt[2][2];
#pragma unroll
        for (int j = 0; j < 2; ++j)
#pragma unroll
            for (int s = 0; s < 2; ++s) b_cur[j][s] = DS_B(0, j, s);

        for (int C = 0; C < NKT; ++C) {
            const int cb = C & 1, nb = cb ^ 1;

            // ---- p0: read A(m0-3) x8 + B(n2,n3) x4 ; stage B0(C+1) ; SBAR ; MFMA Q0
#pragma unroll
            for (int i = 0; i < 4; ++i)
#pragma unroll
                for (int s = 0; s < 2; ++s) a[i][s] = DS_A(cb, i, s);
#pragma unroll
            for (int j = 0; j < 2; ++j)
#pragma unroll
                for (int s = 0; s < 2; ++s) b_hi[j][s] = DS_B(cb, 2 + j, s);
            if (C < NKT - 1) STG_B(nb, 0, C + 1);
            SBAR();
            __builtin_amdgcn_s_setprio(1);
#pragma unroll
            for (int s = 0; s < 2; ++s)
#pragma unroll
                for (int i = 0; i < 4; ++i)
#pragma unroll
                    for (int j = 0; j < 2; ++j)
                        acc[i][j] = __builtin_amdgcn_mfma_i32_16x16x64_i8(a[i][s], b_cur[j][s], acc[i][j], 0, 0, 0);
            __builtin_amdgcn_s_setprio(0);

            // ---- p1 (no barrier): stage B1(C+1) ; MFMA Q1
            if (C < NKT - 1) STG_B(nb, 1, C + 1);
            __builtin_amdgcn_s_setprio(1);
#pragma unroll
            for (int s = 0; s < 2; ++s)
#pragma unroll
                for (int i = 0; i < 4; ++i)
#pragma unroll
                    for (int j = 0; j < 2; ++j)
                        acc[i][2 + j] = __builtin_amdgcn_mfma_i32_16x16x64_i8(a[i][s], b_hi[j][s], acc[i][2 + j], 0, 0, 0);
            __builtin_amdgcn_s_setprio(0);

            // ---- p2: read A(m4-7) x8 ; stage A1(C+1) ; vmcnt(2) ; SBAR ; MFMA Q2
#pragma unroll
            for (int i = 0; i < 4; ++i)
#pragma unroll
                for (int s = 0; s < 2; ++s) a[i][s] = DS_A(cb, 4 + i, s);
            if (C < NKT - 1) {
                STG_A(nb, 1, C + 1);
                VMCNT(2);
            }
            SBAR();
            __builtin_amdgcn_s_setprio(1);
#pragma unroll
            for (int s = 0; s < 2; ++s)
#pragma unroll
                for (int i = 0; i < 4; ++i)
#pragma unroll
                    for (int j = 0; j < 2; ++j)
                        acc[4 + i][j] = __builtin_amdgcn_mfma_i32_16x16x64_i8(a[i][s], b_cur[j][s], acc[4 + i][j], 0, 0, 0);
            __builtin_amdgcn_s_setprio(0);

            // ---- p3: lookahead read B(n0,n1) of C+1 ; stage A0(C+2) ; vmcnt ; SBAR ; MFMA Q3
            if (C < NKT - 1) {
#pragma unroll
                for (int j = 0; j < 2; ++j)
#pragma unroll
                    for (int s = 0; s < 2; ++s) b_nxt[j][s] = DS_B(nb, j, s);
                if (C < NKT - 2) {
                    STG_A(cb, 0, C + 2);
                    VMCNT(2);
                } else {
                    VMCNT(0);
                }
            }
            SBAR();
            __builtin_amdgcn_s_setprio(1);
#pragma unroll
            for (int s = 0; s < 2; ++s)
#pragma unroll
                for (int i = 0; i < 4; ++i)
#pragma unroll
                    for (int j = 0; j < 2; ++j)
                        acc[4 + i][2 + j] = __builtin_amdgcn_mfma_i32_16x16x64_i8(a[i][s], b_hi[j][s], acc[4 + i][2 + j], 0, 0, 0);
            __builtin_amdgcn_s_setprio(0);

            if (C < NKT - 1) {
#pragma unroll
                for (int j = 0; j < 2; ++j)
#pragma unroll
                    for (int s = 0; s < 2; ++s) b_cur[j][s] = b_nxt[j][s];
            }
        }

        // epilogue: d2 = s^2*(|qi|^2+|qj|^2-2*qi.qj)  (int32 exact), exp-sum
        int rn[8][4];
#pragma unroll
        for (int m = 0; m < 8; ++m)
#pragma unroll
            for (int v = 0; v < 4; ++v)
                rn[m][v] = zn[rA + wr * 128 + m * 16 + fg * 4 + v];
        int cn[4];
#pragma unroll
        for (int n = 0; n < 4; ++n) cn[n] = zn[rB + wc * 64 + n * 16 + fr];

        float ls0 = 0.0f, ls1 = 0.0f;
#pragma unroll
        for (int m = 0; m < 8; ++m)
#pragma unroll
            for (int n = 0; n < 4; ++n)
#pragma unroll
                for (int v = 0; v < 4; ++v) {
                    int d2i = rn[m][v] + cn[n] - 2 * acc[m][n][v];
                    float e = __expf((float)d2i * KFAC);
                    if (v & 1) ls1 += e; else ls0 += e;
                }

        double d = (double)(ls0 + ls1);
#pragma unroll
        for (int o = 32; o > 0; o >>= 1) d += __shfl_down(d, o);
        if (l == 0) red[wid] = d;
        __syncthreads();
        if (tid == 0) {
            double t = 0.0;
#pragma unroll
            for (int i = 0; i < 8; ++i) t += red[i];
            partials[pid] = t * (double)factor;
        }
        if (pp + 1 < npairs) __syncthreads();
    }
#undef STG_A
#undef STG_B
#undef DS_A
#undef DS_B
}

__global__ __launch_bounds__(256) void mmd_reduce(const double* __restrict__ partials,
                                                  float* __restrict__ out, int n) {
    __shared__ double red[256];
    double s = 0.0;
    for (int i = threadIdx.x; i < n; i += 256) s += partials[i];
    red[threadIdx.x] = s;
    __syncthreads();
    for (int ofs = 128; ofs > 0; ofs >>= 1) {
        if (threadIdx.x < ofs) red[threadIdx.x] += red[threadIdx.x + ofs];
        __syncthreads();
    }
    if (threadIdx.x == 0)
        out[0] = (float)(red[0] / ((double)N_ROWS * (double)N_ROWS));
}

// ---- fallback fp32 path (R1, proven) ----
__global__ __launch_bounds__(256) void mmd_norms_f32(const float* __restrict__ x,
                                                     const float* __restrict__ y,
                                                     float* __restrict__ zn) {
    int row = blockIdx.x * 4 + (threadIdx.x >> 6);
    int lane = threadIdx.x & 63;
    const float* p = (row < N_ROWS) ? (x + (size_t)row * DIM)
                                    : (y + (size_t)(row - N_ROWS) * DIM);
    float s = 0.0f;
#pragma unroll
    for (int c = 0; c < 4; ++c) {
        float4 v = *(const float4*)(p + (size_t)(lane + c * 64) * 4);
        s = fmaf(v.x, v.x, s);
        s = fmaf(v.y, v.y, s);
        s = fmaf(v.z, v.z, s);
        s = fmaf(v.w, v.w, s);
    }
#pragma unroll
    for (int o = 32; o > 0; o >>= 1) s += __shfl_down(s, o);
    if (lane == 0) zn[row] = s;
}

__global__ __launch_bounds__(256) void mmd_main_f32(const float* __restrict__ x,
                                                    const float* __restrict__ y,
                                                    const float* __restrict__ zn,
                                                    double* __restrict__ partials) {
    int bid = blockIdx.x;
    int tj = (int)((sqrtf(8.0f * (float)bid + 1.0f) - 1.0f) * 0.5f);
    while ((tj + 1) * (tj + 2) / 2 <= bid) ++tj;
    while (tj * (tj + 1) / 2 > bid) --tj;
    int ti = bid - tj * (tj + 1) / 2;

    const float* A = (ti < 64) ? (x + (size_t)ti * 128 * DIM)
                               : (y + (size_t)(ti - 64) * 128 * DIM);
    const float* B = (tj < 64) ? (x + (size_t)tj * 128 * DIM)
                               : (y + (size_t)(tj - 64) * 128 * DIM);
    float w = ((ti < 64) == (tj < 64)) ? 1.0f : -1.0f;
    float factor = (ti == tj) ? w : 2.0f * w;

    __shared__ float fsa[32][128];
    __shared__ float fsb[32][128];
    __shared__ double red[256];

    int tid = threadIdx.x;
    int tx = tid & 15;
    int ty = tid >> 4;

    float acc[8][8];
#pragma unroll
    for (int r = 0; r < 8; ++r)
#pragma unroll
        for (int s = 0; s < 8; ++s) acc[r][s] = 0.0f;

    for (int k0 = 0; k0 < DIM; k0 += 32) {
#pragma unroll
        for (int u = 0; u < 4; ++u) {
            int f = tid + u * 256;
            int row = f >> 3;
            int kk = (f & 7) << 2;
            float4 va = *(const float4*)(A + (size_t)row * DIM + k0 + kk);
            float4 vb = *(const float4*)(B + (size_t)row * DIM + k0 + kk);
            fsa[kk + 0][row] = va.x; fsa[kk + 1][row] = va.y;
            fsa[kk + 2][row] = va.z; fsa[kk + 3][row] = va.w;
            fsb[kk + 0][row] = vb.x; fsb[kk + 1][row] = vb.y;
            fsb[kk + 2][row] = vb.z; fsb[kk + 3][row] = vb.w;
        }
        __syncthreads();
#pragma unroll 8
        for (int k = 0; k < 32; ++k) {
            float4 a0 = *(const float4*)&fsa[k][ty * 8];
            float4 a1 = *(const float4*)&fsa[k][ty * 8 + 4];
            float4 b0 = *(const float4*)&fsb[k][tx * 8];
            float4 b1 = *(const float4*)&fsb[k][tx * 8 + 4];
            float af[8] = {a0.x, a0.y, a0.z, a0.w, a1.x, a1.y, a1.z, a1.w};
            float bfv[8] = {b0.x, b0.y, b0.z, b0.w, b1.x, b1.y, b1.z, b1.w};
#pragma unroll
            for (int r = 0; r < 8; ++r)
#pragma unroll
                for (int s = 0; s < 8; ++s)
                    acc[r][s] = fmaf(af[r], bfv[s], acc[r][s]);
        }
        __syncthreads();
    }

    float xnrm[8], ynrm[8];
#pragma unroll
    for (int r = 0; r < 8; ++r) xnrm[r] = zn[ti * 128 + ty * 8 + r];
#pragma unroll
    for (int s = 0; s < 8; ++s) ynrm[s] = zn[tj * 128 + tx * 8 + s];

    float lsum = 0.0f;
#pragma unroll
    for (int r = 0; r < 8; ++r)
#pragma unroll
        for (int s = 0; s < 8; ++s) {
            float d2 = fmaf(-2.0f, acc[r][s], xnrm[r] + ynrm[s]);
            lsum += __expf(-d2 / 2048.0f);
        }

    red[tid] = (double)lsum;
    __syncthreads();
#pragma unroll
    for (int ofs = 128; ofs > 0; ofs >>= 1) {
        if (tid < ofs) red[tid] += red[tid + ofs];
        __syncthreads();
    }
    if (tid == 0) partials[bid] = red[0] * (double)factor;
}

extern "C" void kernel_launch(void* const* d_in, const int* in_sizes, int n_in,
                              void* d_out, int out_size, void* d_ws, size_t ws_size,
                              hipStream_t stream) {
    const float* x = (const float*)d_in[0];
    const float* y = (const float*)d_in[1];
    float* out = (float*)d_out;

    const size_t zq_bytes = (size_t)TWO_N * DIM;              // 16 MiB (i8)
    const size_t zn_bytes = (size_t)TWO_N * sizeof(int);      // 64 KiB
    const size_t pt_bytes = (size_t)NBLK2 * sizeof(double);
    const size_t need = zq_bytes + zn_bytes + pt_bytes;

    if (ws_size >= need) {
        int* zq = (int*)d_ws;
        int* zn = (int*)((char*)d_ws + zq_bytes);
        double* partials = (double*)((char*)d_ws + zq_bytes + zn_bytes);
        mmd_convert_i8<<<TWO_N / 4, 256, 0, stream>>>(x, y, zq, zn);
        mmd_main_i8<<<GRID2, 512, 0, stream>>>((const char*)zq, zn, partials);
        mmd_reduce<<<1, 256, 0, stream>>>(partials, out, NBLK2);
    } else {
        float* zn = (float*)d_ws;
        double* partials = (double*)((char*)d_ws + (size_t)TWO_N * sizeof(float));
        mmd_norms_f32<<<TWO_N / 4, 256, 0, stream>>>(x, y, zn);
        mmd_main_f32<<<128 * 129 / 2, 256, 0, stream>>>(x, y, zn, partials);
        mmd_reduce<<<1, 256, 0, stream>>>(partials, out, 128 * 129 / 2);
    }
}

// Round 20
// 183.251 us; speedup vs baseline: 1.0215x; 1.0215x over previous
//
#include <hip/hip_runtime.h>
#include <hip/hip_bf16.h>

// GaussianMMD: out = mean(Kxx)+mean(Kyy)-2*mean(Kxy), K=exp(-||a-b||^2/2048)
// R20 = R18 restored verbatim (best benched: 183.4us total, absmax 0).
// int8 MFMA BK=128B, exact int32 Gram (fixed scale 6/127), 4-phase with ONE
// barrier per phase (reads->stage->[vmcnt]->SBAR->MFMA), grid-2048 two-pair
// tail fix, bh-hoist at p0, T2 swizzle, T5 setprio, XCD swizzle.
// R19's 3-barrier variant was neutral-negative -> 4 barriers/K-tile is the floor.

#define N_ROWS 8192
#define DIM 1024
#define TWO_N 16384
#define BT 256
#define BKB 128                      // K-tile in BYTES (i8 elems)
#define NT2 64
#define NBLK2 (NT2 * (NT2 + 1) / 2) // 2080
#define GRID2 2048
#define NKT (DIM / BKB)             // 8
#define QSCL (127.0f / 6.0f)
#define S2 ((6.0f / 127.0f) * (6.0f / 127.0f))
#define KFAC (-S2 / 2048.0f)

typedef int i32x4 __attribute__((ext_vector_type(4)));

typedef __attribute__((address_space(3))) unsigned int lds_u32_t;
typedef const __attribute__((address_space(1))) unsigned int glb_u32_t;

__device__ __forceinline__ void gload16(const void* g, void* l) {
    __builtin_amdgcn_global_load_lds((glb_u32_t*)g, (lds_u32_t*)l, 16, 0, 0);
}

#define SBAR() do { __builtin_amdgcn_sched_barrier(0); \
                    __builtin_amdgcn_s_barrier();      \
                    __builtin_amdgcn_sched_barrier(0); } while (0)
#define VMCNT(n) asm volatile("s_waitcnt vmcnt(" #n ")" ::: "memory")

// ---- convert fp32 -> int8 (fixed scale), norms in exact int32 ----
__global__ __launch_bounds__(256) void mmd_convert_i8(const float* __restrict__ x,
                                                      const float* __restrict__ y,
                                                      int* __restrict__ zq,
                                                      int* __restrict__ zn) {
    int row = blockIdx.x * 4 + (threadIdx.x >> 6);
    int lane = threadIdx.x & 63;
    const float* p = (row < N_ROWS) ? (x + (size_t)row * DIM)
                                    : (y + (size_t)(row - N_ROWS) * DIM);
    int* q = zq + (size_t)row * (DIM / 4);
    int s = 0;
#pragma unroll
    for (int c = 0; c < 4; ++c) {
        int widx = lane + c * 64;
        float4 v = *(const float4*)(p + widx * 4);
        int q0 = (int)rintf(fminf(fmaxf(v.x * QSCL, -127.0f), 127.0f));
        int q1 = (int)rintf(fminf(fmaxf(v.y * QSCL, -127.0f), 127.0f));
        int q2 = (int)rintf(fminf(fmaxf(v.z * QSCL, -127.0f), 127.0f));
        int q3 = (int)rintf(fminf(fmaxf(v.w * QSCL, -127.0f), 127.0f));
        s += q0 * q0 + q1 * q1 + q2 * q2 + q3 * q3;
        q[widx] = (q0 & 0xff) | ((q1 & 0xff) << 8) | ((q2 & 0xff) << 16) | ((q3 & 0xff) << 24);
    }
#pragma unroll
    for (int o = 32; o > 0; o >>= 1) s += __shfl_down(s, o);
    if (lane == 0) zn[row] = s;
}

// ---- main: 256x256 tile, 8 waves, 4-phase (1 barrier/phase), BK=128 i8 ----
__global__ __launch_bounds__(512, 2) void mmd_main_i8(const char* __restrict__ zq,
                                                      const int* __restrict__ zn,
                                                      double* __restrict__ partials) {
    __shared__ __align__(16) char lsA[2][BT * BKB];  // 64 KiB
    __shared__ __align__(16) char lsB[2][BT * BKB];  // 64 KiB
    __shared__ double red[8];

    const int tid = threadIdx.x;
    const int bid0 = blockIdx.x;

    const int l = tid & 63;
    const int wid = tid >> 6;
    const int wr = wid >> 2;  // 0..1
    const int wc = wid & 3;   // 0..3
    const int fr = l & 15;
    const int fg = l >> 4;    // 16B-chunk within 64-K half

    // staging: thread t -> LDS row=t>>3 (0..63), slot=t&7; global chunk = slot^(row&7)
    const int srow = tid >> 3;
    const int cswz = ((tid & 7) ^ ((tid >> 3) & 7)) * 16;
    char* lA = &lsA[0][0];
    char* lB = &lsB[0][0];
    const int t16 = tid * 16;

#define STG_A(buf, half, kt) do {                                             \
        const char* g_ = pA + (size_t)((half) * 128) * DIM + (kt) * BKB;      \
        gload16(g_,            lA + (buf) * 32768 + (half) * 16384 + t16);        \
        gload16(g_ + 64 * DIM, lA + (buf) * 32768 + (half) * 16384 + 8192 + t16); \
    } while (0)
#define STG_B(buf, half, kt) do {                                             \
        const char* g_ = pB + (size_t)((half) * 128) * DIM + (kt) * BKB;      \
        gload16(g_,            lB + (buf) * 32768 + (half) * 16384 + t16);        \
        gload16(g_ + 64 * DIM, lB + (buf) * 32768 + (half) * 16384 + 8192 + t16); \
    } while (0)
// frag reads: row r, K-half s, chunk fg -> phys slot (s*4+fg)^(r&7); r&7 == fr&7
#define DS_A(buf, m, s) (*(const i32x4*)(lA + (buf) * 32768 + \
        (wr * 128 + (m) * 16 + fr) * BKB + ((((s) * 4 + fg) ^ (fr & 7)) << 4)))
#define DS_B(buf, n, s) (*(const i32x4*)(lB + (buf) * 32768 + \
        (wc * 64 + (n) * 16 + fr) * BKB + ((((s) * 4 + fg) ^ (fr & 7)) << 4)))

    const int npairs = (bid0 < NBLK2 - GRID2) ? 2 : 1;  // blocks 0..31 do 2 pairs

#pragma unroll 1
    for (int pp = 0; pp < npairs; ++pp) {
        const int pid = pp ? (GRID2 + bid0) : bid0;
        const int bid = (pid & 7) * (NBLK2 / 8) + (pid >> 3);  // XCD swizzle

        int tj = (int)((sqrtf(8.0f * (float)bid + 1.0f) - 1.0f) * 0.5f);
        while ((tj + 1) * (tj + 2) / 2 <= bid) ++tj;
        while (tj * (tj + 1) / 2 > bid) --tj;
        const int ti = bid - tj * (tj + 1) / 2;

        const int rA = ti * BT, rB = tj * BT;
        const float w = ((ti < 32) == (tj < 32)) ? 1.0f : -1.0f;
        const float factor = (ti == tj) ? w : 2.0f * w;

        const char* pA = zq + (size_t)(rA + srow) * DIM + cswz;
        const char* pB = zq + (size_t)(rB + srow) * DIM + cswz;

        i32x4 acc[8][4];
#pragma unroll
        for (int m = 0; m < 8; ++m)
#pragma unroll
            for (int n = 0; n < 4; ++n) acc[m][n] = (i32x4){0, 0, 0, 0};

        // prologue: full tile 0 + A0 of tile 1 (10 loads); retire tile 0
        STG_A(0, 0, 0);
        STG_B(0, 0, 0);
        STG_B(0, 1, 0);
        STG_A(0, 1, 0);
        STG_A(1, 0, 1);
        VMCNT(2);
        SBAR();

        i32x4 a[4][2], b_cur[2][2], b_hi[2][2], b_nxt[2][2];
#pragma unroll
        for (int j = 0; j < 2; ++j)
#pragma unroll
            for (int s = 0; s < 2; ++s) b_cur[j][s] = DS_B(0, j, s);

        for (int C = 0; C < NKT; ++C) {
            const int cb = C & 1, nb = cb ^ 1;

            // ---- p0: read A(m0-3) x8 + B(n2,n3) x4 ; stage B0(C+1) ; SBAR ; MFMA Q0
#pragma unroll
            for (int i = 0; i < 4; ++i)
#pragma unroll
                for (int s = 0; s < 2; ++s) a[i][s] = DS_A(cb, i, s);
#pragma unroll
            for (int j = 0; j < 2; ++j)
#pragma unroll
                for (int s = 0; s < 2; ++s) b_hi[j][s] = DS_B(cb, 2 + j, s);
            if (C < NKT - 1) STG_B(nb, 0, C + 1);
            SBAR();
            __builtin_amdgcn_s_setprio(1);
#pragma unroll
            for (int s = 0; s < 2; ++s)
#pragma unroll
                for (int i = 0; i < 4; ++i)
#pragma unroll
                    for (int j = 0; j < 2; ++j)
                        acc[i][j] = __builtin_amdgcn_mfma_i32_16x16x64_i8(a[i][s], b_cur[j][s], acc[i][j], 0, 0, 0);
            __builtin_amdgcn_s_setprio(0);

            // ---- p1: no reads ; stage B1(C+1) ; SBAR ; MFMA Q1
            if (C < NKT - 1) STG_B(nb, 1, C + 1);
            SBAR();
            __builtin_amdgcn_s_setprio(1);
#pragma unroll
            for (int s = 0; s < 2; ++s)
#pragma unroll
                for (int i = 0; i < 4; ++i)
#pragma unroll
                    for (int j = 0; j < 2; ++j)
                        acc[i][2 + j] = __builtin_amdgcn_mfma_i32_16x16x64_i8(a[i][s], b_hi[j][s], acc[i][2 + j], 0, 0, 0);
            __builtin_amdgcn_s_setprio(0);

            // ---- p2: read A(m4-7) x8 ; stage A1(C+1) ; vmcnt(2) ; SBAR ; MFMA Q2
#pragma unroll
            for (int i = 0; i < 4; ++i)
#pragma unroll
                for (int s = 0; s < 2; ++s) a[i][s] = DS_A(cb, 4 + i, s);
            if (C < NKT - 1) {
                STG_A(nb, 1, C + 1);
                VMCNT(2);
            }
            SBAR();
            __builtin_amdgcn_s_setprio(1);
#pragma unroll
            for (int s = 0; s < 2; ++s)
#pragma unroll
                for (int i = 0; i < 4; ++i)
#pragma unroll
                    for (int j = 0; j < 2; ++j)
                        acc[4 + i][j] = __builtin_amdgcn_mfma_i32_16x16x64_i8(a[i][s], b_cur[j][s], acc[4 + i][j], 0, 0, 0);
            __builtin_amdgcn_s_setprio(0);

            // ---- p3: lookahead read B(n0,n1) of C+1 ; stage A0(C+2) ; vmcnt ; SBAR ; MFMA Q3
            if (C < NKT - 1) {
#pragma unroll
                for (int j = 0; j < 2; ++j)
#pragma unroll
                    for (int s = 0; s < 2; ++s) b_nxt[j][s] = DS_B(nb, j, s);
                if (C < NKT - 2) {
                    STG_A(cb, 0, C + 2);
                    VMCNT(2);
                } else {
                    VMCNT(0);
                }
            }
            SBAR();
            __builtin_amdgcn_s_setprio(1);
#pragma unroll
            for (int s = 0; s < 2; ++s)
#pragma unroll
                for (int i = 0; i < 4; ++i)
#pragma unroll
                    for (int j = 0; j < 2; ++j)
                        acc[4 + i][2 + j] = __builtin_amdgcn_mfma_i32_16x16x64_i8(a[i][s], b_hi[j][s], acc[4 + i][2 + j], 0, 0, 0);
            __builtin_amdgcn_s_setprio(0);

            if (C < NKT - 1) {
#pragma unroll
                for (int j = 0; j < 2; ++j)
#pragma unroll
                    for (int s = 0; s < 2; ++s) b_cur[j][s] = b_nxt[j][s];
            }
        }

        // epilogue: d2 = s^2*(|qi|^2+|qj|^2-2*qi.qj)  (int32 exact), exp-sum
        int rn[8][4];
#pragma unroll
        for (int m = 0; m < 8; ++m)
#pragma unroll
            for (int v = 0; v < 4; ++v)
                rn[m][v] = zn[rA + wr * 128 + m * 16 + fg * 4 + v];
        int cn[4];
#pragma unroll
        for (int n = 0; n < 4; ++n) cn[n] = zn[rB + wc * 64 + n * 16 + fr];

        float ls0 = 0.0f, ls1 = 0.0f;
#pragma unroll
        for (int m = 0; m < 8; ++m)
#pragma unroll
            for (int n = 0; n < 4; ++n)
#pragma unroll
                for (int v = 0; v < 4; ++v) {
                    int d2i = rn[m][v] + cn[n] - 2 * acc[m][n][v];
                    float e = __expf((float)d2i * KFAC);
                    if (v & 1) ls1 += e; else ls0 += e;
                }

        double d = (double)(ls0 + ls1);
#pragma unroll
        for (int o = 32; o > 0; o >>= 1) d += __shfl_down(d, o);
        if (l == 0) red[wid] = d;
        __syncthreads();
        if (tid == 0) {
            double t = 0.0;
#pragma unroll
            for (int i = 0; i < 8; ++i) t += red[i];
            partials[pid] = t * (double)factor;
        }
        if (pp + 1 < npairs) __syncthreads();
    }
#undef STG_A
#undef STG_B
#undef DS_A
#undef DS_B
}

__global__ __launch_bounds__(256) void mmd_reduce(const double* __restrict__ partials,
                                                  float* __restrict__ out, int n) {
    __shared__ double red[256];
    double s = 0.0;
    for (int i = threadIdx.x; i < n; i += 256) s += partials[i];
    red[threadIdx.x] = s;
    __syncthreads();
    for (int ofs = 128; ofs > 0; ofs >>= 1) {
        if (threadIdx.x < ofs) red[threadIdx.x] += red[threadIdx.x + ofs];
        __syncthreads();
    }
    if (threadIdx.x == 0)
        out[0] = (float)(red[0] / ((double)N_ROWS * (double)N_ROWS));
}

// ---- fallback fp32 path (R1, proven) ----
__global__ __launch_bounds__(256) void mmd_norms_f32(const float* __restrict__ x,
                                                     const float* __restrict__ y,
                                                     float* __restrict__ zn) {
    int row = blockIdx.x * 4 + (threadIdx.x >> 6);
    int lane = threadIdx.x & 63;
    const float* p = (row < N_ROWS) ? (x + (size_t)row * DIM)
                                    : (y + (size_t)(row - N_ROWS) * DIM);
    float s = 0.0f;
#pragma unroll
    for (int c = 0; c < 4; ++c) {
        float4 v = *(const float4*)(p + (size_t)(lane + c * 64) * 4);
        s = fmaf(v.x, v.x, s);
        s = fmaf(v.y, v.y, s);
        s = fmaf(v.z, v.z, s);
        s = fmaf(v.w, v.w, s);
    }
#pragma unroll
    for (int o = 32; o > 0; o >>= 1) s += __shfl_down(s, o);
    if (lane == 0) zn[row] = s;
}

__global__ __launch_bounds__(256) void mmd_main_f32(const float* __restrict__ x,
                                                    const float* __restrict__ y,
                                                    const float* __restrict__ zn,
                                                    double* __restrict__ partials) {
    int bid = blockIdx.x;
    int tj = (int)((sqrtf(8.0f * (float)bid + 1.0f) - 1.0f) * 0.5f);
    while ((tj + 1) * (tj + 2) / 2 <= bid) ++tj;
    while (tj * (tj + 1) / 2 > bid) --tj;
    int ti = bid - tj * (tj + 1) / 2;

    const float* A = (ti < 64) ? (x + (size_t)ti * 128 * DIM)
                               : (y + (size_t)(ti - 64) * 128 * DIM);
    const float* B = (tj < 64) ? (x + (size_t)tj * 128 * DIM)
                               : (y + (size_t)(tj - 64) * 128 * DIM);
    float w = ((ti < 64) == (tj < 64)) ? 1.0f : -1.0f;
    float factor = (ti == tj) ? w : 2.0f * w;

    __shared__ float fsa[32][128];
    __shared__ float fsb[32][128];
    __shared__ double red[256];

    int tid = threadIdx.x;
    int tx = tid & 15;
    int ty = tid >> 4;

    float acc[8][8];
#pragma unroll
    for (int r = 0; r < 8; ++r)
#pragma unroll
        for (int s = 0; s < 8; ++s) acc[r][s] = 0.0f;

    for (int k0 = 0; k0 < DIM; k0 += 32) {
#pragma unroll
        for (int u = 0; u < 4; ++u) {
            int f = tid + u * 256;
            int row = f >> 3;
            int kk = (f & 7) << 2;
            float4 va = *(const float4*)(A + (size_t)row * DIM + k0 + kk);
            float4 vb = *(const float4*)(B + (size_t)row * DIM + k0 + kk);
            fsa[kk + 0][row] = va.x; fsa[kk + 1][row] = va.y;
            fsa[kk + 2][row] = va.z; fsa[kk + 3][row] = va.w;
            fsb[kk + 0][row] = vb.x; fsb[kk + 1][row] = vb.y;
            fsb[kk + 2][row] = vb.z; fsb[kk + 3][row] = vb.w;
        }
        __syncthreads();
#pragma unroll 8
        for (int k = 0; k < 32; ++k) {
            float4 a0 = *(const float4*)&fsa[k][ty * 8];
            float4 a1 = *(const float4*)&fsa[k][ty * 8 + 4];
            float4 b0 = *(const float4*)&fsb[k][tx * 8];
            float4 b1 = *(const float4*)&fsb[k][tx * 8 + 4];
            float af[8] = {a0.x, a0.y, a0.z, a0.w, a1.x, a1.y, a1.z, a1.w};
            float bfv[8] = {b0.x, b0.y, b0.z, b0.w, b1.x, b1.y, b1.z, b1.w};
#pragma unroll
            for (int r = 0; r < 8; ++r)
#pragma unroll
                for (int s = 0; s < 8; ++s)
                    acc[r][s] = fmaf(af[r], bfv[s], acc[r][s]);
        }
        __syncthreads();
    }

    float xnrm[8], ynrm[8];
#pragma unroll
    for (int r = 0; r < 8; ++r) xnrm[r] = zn[ti * 128 + ty * 8 + r];
#pragma unroll
    for (int s = 0; s < 8; ++s) ynrm[s] = zn[tj * 128 + tx * 8 + s];

    float lsum = 0.0f;
#pragma unroll
    for (int r = 0; r < 8; ++r)
#pragma unroll
        for (int s = 0; s < 8; ++s) {
            float d2 = fmaf(-2.0f, acc[r][s], xnrm[r] + ynrm[s]);
            lsum += __expf(-d2 / 2048.0f);
        }

    red[tid] = (double)lsum;
    __syncthreads();
#pragma unroll
    for (int ofs = 128; ofs > 0; ofs >>= 1) {
        if (tid < ofs) red[tid] += red[tid + ofs];
        __syncthreads();
    }
    if (tid == 0) partials[bid] = red[0] * (double)factor;
}

extern "C" void kernel_launch(void* const* d_in, const int* in_sizes, int n_in,
                              void* d_out, int out_size, void* d_ws, size_t ws_size,
                              hipStream_t stream) {
    const float* x = (const float*)d_in[0];
    const float* y = (const float*)d_in[1];
    float* out = (float*)d_out;

    const size_t zq_bytes = (size_t)TWO_N * DIM;              // 16 MiB (i8)
    const size_t zn_bytes = (size_t)TWO_N * sizeof(int);      // 64 KiB
    const size_t pt_bytes = (size_t)NBLK2 * sizeof(double);
    const size_t need = zq_bytes + zn_bytes + pt_bytes;

    if (ws_size >= need) {
        int* zq = (int*)d_ws;
        int* zn = (int*)((char*)d_ws + zq_bytes);
        double* partials = (double*)((char*)d_ws + zq_bytes + zn_bytes);
        mmd_convert_i8<<<TWO_N / 4, 256, 0, stream>>>(x, y, zq, zn);
        mmd_main_i8<<<GRID2, 512, 0, stream>>>((const char*)zq, zn, partials);
        mmd_reduce<<<1, 256, 0, stream>>>(partials, out, NBLK2);
    } else {
        float* zn = (float*)d_ws;
        double* partials = (double*)((char*)d_ws + (size_t)TWO_N * sizeof(float));
        mmd_norms_f32<<<TWO_N / 4, 256, 0, stream>>>(x, y, zn);
        mmd_main_f32<<<128 * 129 / 2, 256, 0, stream>>>(x, y, zn, partials);
        mmd_reduce<<<1, 256, 0, stream>>>(partials, out, 128 * 129 / 2);
    }
}